// Round 8
// baseline (194.436 us; speedup 1.0000x reference)
//
#include <hip/hip_runtime.h>

// Fused SDPA, MI355X gfx950. G=32, H=8, L=512, D=64.
// q:(G,H,L,D) f32, k:(G,H,D,L) f32, v:(G,H,L,D) f32, mask:(8,L,L) int
// (nonzero = masked), out:(G,H,L,D) f32.
//
// Round 8: SMALL-BLOCK restructure (single variable vs the R2 champion).
// Ledger: every register-prefetch/fat-wave variant lost (spill or TLP loss);
// R2 (68.6us) is latency-bound with all pipes <33%. Residual serializer =
// phase lock-step: only 4 barrier domains/CU, 16 waves stage together and
// compute together. Fix: block = 2 waves (64 q-rows), grid = 2048 ->
// 8 independent blocks/CU (LDS 16KB x 8 = 128KB), SAME 16 waves/CU.
// Barriers sync 2 waves; 8 de-phased blocks/CU overlap staging with
// compute across blocks. No prefetch, no dbuf: VGPR stays 64, no spill.
// Cost accepted: per-wave staging doubles (VALU was 32% busy), K/V read by
// 8 q-tile blocks/head (vs 4) -- L3-resident (K+V total 64MB < 256MB).
//
// Per-iter: barrier -> stage K,V chunk (bf16 pack, XOR-swizzled b128) ->
// barrier -> 2x [GEMM1 S^T = K x Q -> mask+exp (bitmask) -> GEMM2 O += P x V].
// Lane owns one q-row -> lane-local softmax sum; no running max (scores
// ~N(0,1), exp2 f32 can't overflow).

typedef __attribute__((ext_vector_type(8)))  short bf16x8;
typedef __attribute__((ext_vector_type(16))) float f32x16;

union Frag4 { uint4 x; unsigned u[4]; bf16x8 v; };

// pack two f32 -> packed bf16 pair (a -> low, b -> high), round-half-up
__device__ __forceinline__ unsigned pk_bf16(float a, float b){
    unsigned ua = __builtin_bit_cast(unsigned, a) + 0x8000u;
    unsigned ub = __builtin_bit_cast(unsigned, b) + 0x8000u;
    return __builtin_amdgcn_perm(ub, ua, 0x07060302u);
}

__device__ __forceinline__ float fast_exp2(float x){
#if __has_builtin(__builtin_amdgcn_exp2f)
    return __builtin_amdgcn_exp2f(x);
#else
    return exp2f(x);
#endif
}

#define L2E 1.44269504088896f

// ---- mask pre-pass: (8,512,512) int32 (nonzero=masked) -> 512-bit rows.
__global__ __launch_bounds__(256)
void pack_mask(const int* __restrict__ mg, unsigned long long* __restrict__ bits)
{
    const int t    = blockIdx.x*256 + threadIdx.x;
    const int lane = t & 63;
    const int w0   = t >> 6;
    const int strd = (int)((gridDim.x*256) >> 6);
    const int nW   = 8*512*8;          // 8 batches * 512 rows * 8 u64/row
    for (int i = w0; i < nW; i += strd){
        int v = mg[(size_t)i*64 + lane];
        unsigned long long m = __ballot(v != 0);
        if (lane == 0) bits[i] = m;
    }
}

// fallback mword builder (no-workspace path): bits rg*8+h*4+j of the 32-key
// group starting at p; only this lane's tested bits are populated.
__device__ __forceinline__ unsigned build_mword(const int* p, int h){
    unsigned w = 0;
    #pragma unroll
    for (int rg=0; rg<4; ++rg){
        int4 mm = *(const int4*)(p + rg*8 + h*4);
        const unsigned base = rg*8 + h*4;
        w |= (mm.x?1u:0u) << base;
        w |= (mm.y?1u:0u) << (base+1);
        w |= (mm.z?1u:0u) << (base+2);
        w |= (mm.w?1u:0u) << (base+3);
    }
    return w;
}

template<int BITS>
__global__ __launch_bounds__(128, 4)
void attn_fused(const float* __restrict__ qg, const float* __restrict__ kg,
                const float* __restrict__ vg, const int* __restrict__ mg,
                const unsigned* __restrict__ bits, float* __restrict__ og)
{
    __shared__ uint4 sKt4[64*8];  // Kt[m][d-group g^(m&7)]  8 KiB
    __shared__ uint4 sVt4[64*8];  // Vt[d][m-group g^(d&7)]  8 KiB

    const int t    = threadIdx.x;
    const int lane = t & 63;
    const int wv   = t >> 6;           // 0..1
    const int col  = lane & 31;
    const int h    = lane >> 5;

    // grid = 2048: XCD swizzle (bi&7 == XCD id == mask batch).
    const int bi   = blockIdx.x;
    const int s    = bi >> 3;              // [0,256)
    const int head = (bi & 7)*32 + (s >> 3);
    const int qt   = s & 7;                // 8 q-tiles of 64 rows
    const int b    = bi & 7;

    const float* qh = qg + (size_t)head*32768;
    const float* kh = kg + (size_t)head*32768;
    const float* vh = vg + (size_t)head*32768;
    float*       oh = og + (size_t)head*32768;

    const int qrl  = wv*32 + col;          // q-row within 64-row tile
    const int qrow = qt*64 + qrl;          // q-row within head
    const int* mrow0 = BITS ? nullptr
        : mg + (size_t)b*262144 + (size_t)qrow*512;
    const unsigned* brow = BITS
        ? bits + ((size_t)b*512 + qrow)*16     // 16 dwords = 512 bits/row
        : nullptr;

    // ---- persistent Q B-fragments (pre-scaled 1/8, bf16): B[k=h*8+j][n=col]
    Frag4 qf[4];
    {
        const float* qr = qh + (size_t)qrow*64 + h*8;
        #pragma unroll
        for (int kt=0; kt<4; ++kt){
            float4 x0 = *(const float4*)(qr + kt*16);
            float4 x1 = *(const float4*)(qr + kt*16 + 4);
            qf[kt].u[0] = pk_bf16(x0.x*0.125f, x0.y*0.125f);
            qf[kt].u[1] = pk_bf16(x0.z*0.125f, x0.w*0.125f);
            qf[kt].u[2] = pk_bf16(x1.x*0.125f, x1.y*0.125f);
            qf[kt].u[3] = pk_bf16(x1.z*0.125f, x1.w*0.125f);
        }
    }

    f32x16 o0, o1;        // O[i=q(reg)][j]: o0 -> d=col, o1 -> d=32+col
    #pragma unroll
    for (int i=0;i<16;++i){ o0[i]=0.f; o1[i]=0.f; }
    float lsum = 0.f;     // half-partial softmax denom for q-row qrl

    for (int kb=0; kb<8; ++kb){
        __syncthreads();   // WAR: previous iteration's frag reads done

        // ---- mask bits first (L1-hot line, 8B/lane)
        uint2 mbv;
        if constexpr (BITS) mbv = *(const uint2*)(brow + kb*2);

        // ---- stage K chunk: K[d][kb*64+m] -> Kt[m][d] bf16, swizzled b128
        #pragma unroll
        for (int gi=0; gi<4; ++gi){
            const int g = wv*4 + gi;                     // d-octet index
            const float* kp = kh + (size_t)(g*8)*512 + kb*64 + lane;
            float kv[8];
            #pragma unroll
            for (int dd=0; dd<8; ++dd) kv[dd] = kp[(size_t)dd*512];
            Frag4 w;
            w.u[0]=pk_bf16(kv[0],kv[1]); w.u[1]=pk_bf16(kv[2],kv[3]);
            w.u[2]=pk_bf16(kv[4],kv[5]); w.u[3]=pk_bf16(kv[6],kv[7]);
            sKt4[lane*8 + (g ^ (lane&7))] = w.x;
        }
        // ---- stage V chunk: V[kb*64+m][d] -> Vt[d][m] bf16, swizzled b128
        #pragma unroll
        for (int gi=0; gi<4; ++gi){
            const int g = wv*4 + gi;                     // m-octet index
            const float* vp = vh + (size_t)(kb*64 + g*8)*64 + lane;
            float vv[8];
            #pragma unroll
            for (int mm=0; mm<8; ++mm) vv[mm] = vp[(size_t)mm*64];
            Frag4 w;
            w.u[0]=pk_bf16(vv[0],vv[1]); w.u[1]=pk_bf16(vv[2],vv[3]);
            w.u[2]=pk_bf16(vv[4],vv[5]); w.u[3]=pk_bf16(vv[6],vv[7]);
            sVt4[lane*8 + (g ^ (lane&7))] = w.x;
        }
        __syncthreads();   // RAW: tiles visible

        const int* mrow = BITS ? nullptr : (mrow0 + kb*64);
        #pragma unroll
        for (int mt=0; mt<2; ++mt){
            // ---- GEMM1: S^T[m][q], A = Kt rows (mt*32+col), B = qf
            f32x16 sc;
            #pragma unroll
            for (int i=0;i<16;++i) sc[i]=0.f;
            #pragma unroll
            for (int kt=0; kt<4; ++kt){
                const int r = mt*32 + col;
                Frag4 a; a.x = sKt4[r*8 + ((kt*2+h) ^ (r&7))];
                sc = __builtin_amdgcn_mfma_f32_32x32x16_bf16(a.v, qf[kt].v, sc, 0, 0, 0);
            }
            // ---- mask + exp + lane-local row-sum -> packed bf16 P
            // sc[reg] is m_tile = (reg&3) + 8*(reg>>2) + 4*h, q = own row
            unsigned pp[8];
            if constexpr (BITS){
                const unsigned mword = mt ? mbv.y : mbv.x;   // 32 m-bits
                #pragma unroll
                for (int rg=0; rg<4; ++rg){
                    const unsigned mw = mword >> (rg*8 + h*4);
                    float e0 = (mw & 1u) ? 0.f : fast_exp2(sc[4*rg+0]*L2E);
                    float e1 = (mw & 2u) ? 0.f : fast_exp2(sc[4*rg+1]*L2E);
                    float e2 = (mw & 4u) ? 0.f : fast_exp2(sc[4*rg+2]*L2E);
                    float e3 = (mw & 8u) ? 0.f : fast_exp2(sc[4*rg+3]*L2E);
                    lsum += (e0+e1)+(e2+e3);
                    pp[2*rg]   = pk_bf16(e0, e1);
                    pp[2*rg+1] = pk_bf16(e2, e3);
                }
            } else {
                #pragma unroll
                for (int rg=0; rg<4; ++rg){
                    int4 mm = *(const int4*)(mrow + mt*32 + rg*8 + h*4);
                    float e0 = mm.x ? 0.f : fast_exp2(sc[4*rg+0]*L2E);
                    float e1 = mm.y ? 0.f : fast_exp2(sc[4*rg+1]*L2E);
                    float e2 = mm.z ? 0.f : fast_exp2(sc[4*rg+2]*L2E);
                    float e3 = mm.w ? 0.f : fast_exp2(sc[4*rg+3]*L2E);
                    lsum += (e0+e1)+(e2+e3);
                    pp[2*rg]   = pk_bf16(e0, e1);
                    pp[2*rg+1] = pk_bf16(e2, e3);
                }
            }

            // ---- GEMM2: O += P x V. P A-frag via one half-wave exchange per c.
            #pragma unroll
            for (int c=0; c<2; ++c){
                unsigned keep0 = h ? pp[4*c+2] : pp[4*c+0];
                unsigned keep1 = h ? pp[4*c+3] : pp[4*c+1];
                unsigned give0 = h ? pp[4*c+0] : pp[4*c+2];
                unsigned give1 = h ? pp[4*c+1] : pp[4*c+3];
                unsigned got0 = (unsigned)__shfl_xor((int)give0, 32, 64);
                unsigned got1 = (unsigned)__shfl_xor((int)give1, 32, 64);
                Frag4 pa;
                pa.u[0] = h ? got0  : keep0;   // k-slots 0..1 (from half 0)
                pa.u[1] = h ? got1  : keep1;   // k-slots 2..3
                pa.u[2] = h ? keep0 : got0;    // k-slots 4..5 (from half 1)
                pa.u[3] = h ? keep1 : got1;    // k-slots 6..7
                const int gm = mt*4 + c*2 + h; // m-octet of this half's k-slots
                Frag4 b0; b0.x = sVt4[col*8      + (gm ^ (col&7))];
                o0 = __builtin_amdgcn_mfma_f32_32x32x16_bf16(pa.v, b0.v, o0, 0, 0, 0);
                Frag4 b1; b1.x = sVt4[(32+col)*8 + (gm ^ ((32+col)&7))];
                o1 = __builtin_amdgcn_mfma_f32_32x32x16_bf16(pa.v, b1.v, o1, 0, 0, 0);
            }
        }
    }

    // ---- normalize + direct coalesced stores (O rows: q = (r&3)+8*(r>>2)+4h)
    lsum += __shfl_xor(lsum, 32, 64);
    const float inv = 1.0f / lsum;       // valid at lane (col) for q-row col
    float* ob = oh + (size_t)(qt*64 + wv*32)*64;
    #pragma unroll
    for (int r=0; r<16; ++r){
        const int qq = (r&3) + 8*(r>>2) + 4*h;
        const float iv = __shfl(inv, qq, 64);
        ob[(size_t)qq*64 + col]      = o0[r]*iv;
        ob[(size_t)qq*64 + 32 + col] = o1[r]*iv;
    }
}

extern "C" void kernel_launch(void* const* d_in, const int* in_sizes, int n_in,
                              void* d_out, int out_size, void* d_ws, size_t ws_size,
                              hipStream_t stream) {
    (void)in_sizes; (void)n_in; (void)out_size;
    const float* q = (const float*)d_in[0];
    const float* k = (const float*)d_in[1];
    const float* v = (const float*)d_in[2];
    const int*   m = (const int*)d_in[3];
    const size_t BITS_BYTES = (size_t)8*512*64;   // 256 KiB of packed mask bits
    if (d_ws && ws_size >= BITS_BYTES){
        pack_mask<<<dim3(1024), dim3(256), 0, stream>>>(m, (unsigned long long*)d_ws);
        attn_fused<1><<<dim3(2048), dim3(128), 0, stream>>>(
            q, k, v, m, (const unsigned*)d_ws, (float*)d_out);
    } else {
        attn_fused<0><<<dim3(2048), dim3(128), 0, stream>>>(
            q, k, v, m, nullptr, (float*)d_out);
    }
}